// Round 1
// baseline (540.641 us; speedup 1.0000x reference)
//
#include <hip/hip_runtime.h>
#include <math.h>
#include <stdlib.h>

#define B 4
#define N 1024
#define D 64
#define H 8
#define DH 64
#define INNER 512
#define C3 1536

// ---------------- prep: xT and row sumsq ----------------
__global__ void k_prep(const float* __restrict__ x, float* __restrict__ xT, float* __restrict__ sq) {
    int b = blockIdx.x >> 10, i = blockIdx.x & 1023, t = threadIdx.x; // 64 threads
    float v = x[(b * N + i) * D + t];
    xT[(b * D + t) * N + i] = v;
    float s = v * v;
#pragma unroll
    for (int m = 32; m; m >>= 1) s += __shfl_xor(s, m, 64);
    if (t == 0) sq[b * N + i] = s;
}

// ---------------- spa: constant grid Gaussian, thresholded ----------------
__global__ void k_spa(float* __restrict__ spa, float inv2s2, float mu) {
    int flat4 = blockIdx.x * 256 + threadIdx.x;   // 0..262143 (f4 units)
    int i = flat4 >> 8;
    int j0 = (flat4 & 255) * 4;
    int ix = i >> 6, iy = (i >> 2) & 15, iz = i & 3;
    float4 o;
    float* op = (float*)&o;
#pragma unroll
    for (int jj = 0; jj < 4; jj++) {
        int j = j0 + jj;
        int jx = j >> 6, jy = (j >> 2) & 15, jz = j & 3;
        float d2 = (float)((ix - jx) * (ix - jx) + (iy - jy) * (iy - jy) + (iz - jz) * (iz - jz));
        float w = expf(-d2 * inv2s2);
        op[jj] = (w < mu) ? 0.f : w;
    }
    ((float4*)spa)[flat4] = o;
}

// ---------------- qkv: x @ W_qkv + b, elu+1 on q/k, head layout ----------------
__global__ __launch_bounds__(256) void k_qkv(const float* __restrict__ x, const float* __restrict__ Wqkv,
                                             const float* __restrict__ bqkv, float* __restrict__ qe,
                                             float* __restrict__ ke, float* __restrict__ v) {
    __shared__ float x_s[8 * 64];
    int t = threadIdx.x;
    int b = blockIdx.x >> 7;
    int i0 = (blockIdx.x & 127) * 8;
#pragma unroll
    for (int k = 0; k < 2; k++) {
        int idx = t + 256 * k;
        x_s[idx] = x[(b * N + i0 + (idx >> 6)) * D + (idx & 63)];
    }
    __syncthreads();
    const float4* x_s4 = (const float4*)x_s;
#pragma unroll
    for (int ci = 0; ci < 6; ci++) {
        int c = ci * 256 + t;
        float bias = bqkv[c];
        float acc[8];
#pragma unroll
        for (int r = 0; r < 8; r++) acc[r] = bias;
        for (int d4 = 0; d4 < 16; d4++) {
            int d = d4 * 4;
            float w0 = Wqkv[(d + 0) * C3 + c];
            float w1 = Wqkv[(d + 1) * C3 + c];
            float w2 = Wqkv[(d + 2) * C3 + c];
            float w3 = Wqkv[(d + 3) * C3 + c];
#pragma unroll
            for (int r = 0; r < 8; r++) {
                float4 xv = x_s4[r * 16 + d4];
                acc[r] = fmaf(xv.x, w0, acc[r]);
                acc[r] = fmaf(xv.y, w1, acc[r]);
                acc[r] = fmaf(xv.z, w2, acc[r]);
                acc[r] = fmaf(xv.w, w3, acc[r]);
            }
        }
        int seg = c >> 9;       // 0=q 1=k 2=v
        int cc = c & 511;
        int h = cc >> 6, dh = cc & 63;
#pragma unroll
        for (int r = 0; r < 8; r++) {
            float val = acc[r];
            int off = ((b * H + h) * N + (i0 + r)) * DH + dh;
            if (seg == 0)
                qe[off] = val > 0.f ? val + 1.f : expf(val);
            else if (seg == 1)
                ke[off] = val > 0.f ? val + 1.f : expf(val);
            else
                v[off] = val;
        }
    }
}

// ---------------- gram: d2 = sqi + sqj - 2 x.x^T, + sum of dist ----------------
__global__ __launch_bounds__(256) void k_gram(const float* __restrict__ x, const float* __restrict__ xT,
                                              const float* __restrict__ sq, float* __restrict__ w,
                                              float* __restrict__ d_sig) {
    __shared__ float xi_s[16 * 64];
    __shared__ float sqi_s[16];
    __shared__ float red[4];
    int t = threadIdx.x;
    int b = blockIdx.y;
    int i0 = blockIdx.x * 16;
#pragma unroll
    for (int k = 0; k < 4; k++) {
        int idx = t + 256 * k;
        xi_s[idx] = x[(b * N + i0 + (idx >> 6)) * D + (idx & 63)];
    }
    if (t < 16) sqi_s[t] = sq[b * N + i0 + t];
    __syncthreads();
    const float4* xi_s4 = (const float4*)xi_s;
    float part = 0.f;
    for (int jt = 0; jt < 4; jt++) {
        int j = jt * 256 + t;
        float acc[16];
#pragma unroll
        for (int r = 0; r < 16; r++) acc[r] = 0.f;
        for (int d4 = 0; d4 < 16; d4++) {
            int d = d4 * 4;
            float v0 = xT[(b * D + d + 0) * N + j];
            float v1 = xT[(b * D + d + 1) * N + j];
            float v2 = xT[(b * D + d + 2) * N + j];
            float v3 = xT[(b * D + d + 3) * N + j];
#pragma unroll
            for (int r = 0; r < 16; r++) {
                float4 xi = xi_s4[r * 16 + d4];
                acc[r] = fmaf(xi.x, v0, acc[r]);
                acc[r] = fmaf(xi.y, v1, acc[r]);
                acc[r] = fmaf(xi.z, v2, acc[r]);
                acc[r] = fmaf(xi.w, v3, acc[r]);
            }
        }
        float sqj = sq[b * N + j];
#pragma unroll
        for (int r = 0; r < 16; r++) {
            float d2 = sqi_s[r] + sqj - 2.f * acc[r];
            d2 = fmaxf(d2, 0.f);
            w[(b * N + i0 + r) * N + j] = d2;
            part += (d2 > 1e-12f) ? sqrtf(d2) : 0.f;
        }
    }
#pragma unroll
    for (int m = 32; m; m >>= 1) part += __shfl_xor(part, m, 64);
    if ((t & 63) == 0) red[t >> 6] = part;
    __syncthreads();
    if (t == 0) atomicAdd(d_sig, red[0] + red[1] + red[2] + red[3]);
}

// ---------------- wexp: w = exp(-d2/(2 sigma^2)), + sum w ----------------
__global__ __launch_bounds__(256) void k_wexp(float* __restrict__ w, const float* __restrict__ d_sig,
                                              float* __restrict__ d_wsum) {
    __shared__ float red[4];
    int idx = blockIdx.x * 256 + threadIdx.x;      // f4 index, 1048576 total
    float sigma = d_sig[0] * (1.f / 4194304.f);
    float inv = 1.f / (2.f * sigma * sigma);
    float4 v = ((float4*)w)[idx];
    v.x = expf(-v.x * inv);
    v.y = expf(-v.y * inv);
    v.z = expf(-v.z * inv);
    v.w = expf(-v.w * inv);
    ((float4*)w)[idx] = v;
    float s = v.x + v.y + v.z + v.w;
#pragma unroll
    for (int m = 32; m; m >>= 1) s += __shfl_xor(s, m, 64);
    if ((threadIdx.x & 63) == 0) red[threadIdx.x >> 6] = s;
    __syncthreads();
    if (threadIdx.x == 0) atomicAdd(d_wsum, red[0] + red[1] + red[2] + red[3]);
}

// ---------------- attention: flash-style, 16 rows x 128-wide tiles ----------------
__global__ __launch_bounds__(256) void k_attn(const float* __restrict__ qe, const float* __restrict__ ke,
                                              const float* __restrict__ v, const float* __restrict__ w,
                                              const float* __restrict__ spa, const float* __restrict__ d_wsum,
                                              float* __restrict__ attn_out) {
    __shared__ float4 k_s4[128 * 16];   // [j][slot^ (j&15)]  (XOR-swizzled)
    __shared__ float4 v_s4[128 * 16];   // [j][d4]
    __shared__ float s_s[16 * 128];
    __shared__ float4 qe_s4[16 * 16];
    __shared__ float m_s[16], l_s[16], f_s[16];
    int t = threadIdx.x;
    int i0 = blockIdx.x * 16;
    int h = blockIdx.y, b = blockIdx.z;
    int bh = b * H + h;
    float mu = d_wsum[0] * (1.f / 4194304.f);
    float* qe_s = (float*)qe_s4;
#pragma unroll
    for (int k = 0; k < 4; k++) {
        int idx = t + 256 * k;
        qe_s[idx] = qe[(bh * N + i0 + (idx >> 6)) * DH + (idx & 63)];
    }
    if (t < 16) { m_s[t] = -INFINITY; l_s[t] = 0.f; }

    float accO[8][2] = {};
    int part = t >> 6;            // PV j-part 0..3
    int dbase = (t & 31) * 2;     // PV d
    int rbaseP = ((t >> 5) & 1) * 8;
    int rbaseQ = (t >> 6) * 4;    // QK rows
    int jl = t & 63;
    const float scale = 0.125f;

    for (int tile = 0; tile < 8; tile++) {
        int j0 = tile * 128;
        __syncthreads();
        // stage K (swizzled) and V tiles
#pragma unroll
        for (int k = 0; k < 8; k++) {
            int idx = t + 256 * k;           // 0..2047
            int j = idx >> 4, s = idx & 15;
            int src = (bh * N + j0 + j) * 16 + s;   // f4 units
            k_s4[j * 16 + (s ^ (j & 15))] = ((const float4*)ke)[src];
            v_s4[j * 16 + s] = ((const float4*)v)[src];
        }
        __syncthreads();
        // QK: 4 rows x 2 j per thread
        {
            float acc[4][2] = {};
#pragma unroll
            for (int d4 = 0; d4 < 16; d4++) {
                float4 k0 = k_s4[jl * 16 + (d4 ^ (jl & 15))];
                float4 k1 = k_s4[(jl + 64) * 16 + (d4 ^ (jl & 15))];
#pragma unroll
                for (int r = 0; r < 4; r++) {
                    float4 q = qe_s4[(rbaseQ + r) * 16 + d4];
                    acc[r][0] = fmaf(q.x, k0.x, acc[r][0]);
                    acc[r][0] = fmaf(q.y, k0.y, acc[r][0]);
                    acc[r][0] = fmaf(q.z, k0.z, acc[r][0]);
                    acc[r][0] = fmaf(q.w, k0.w, acc[r][0]);
                    acc[r][1] = fmaf(q.x, k1.x, acc[r][1]);
                    acc[r][1] = fmaf(q.y, k1.y, acc[r][1]);
                    acc[r][1] = fmaf(q.z, k1.z, acc[r][1]);
                    acc[r][1] = fmaf(q.w, k1.w, acc[r][1]);
                }
            }
#pragma unroll
            for (int r = 0; r < 4; r++) {
                int i = i0 + rbaseQ + r;
#pragma unroll
                for (int jj = 0; jj < 2; jj++) {
                    int jloc = jl + jj * 64;
                    int jg = j0 + jloc;
                    float wv = w[(b * N + i) * N + jg];
                    float spe = (wv < mu) ? 0.f : wv;
                    float sp = spa[i * N + jg];
                    s_s[(rbaseQ + r) * 128 + jloc] = acc[r][jj] * scale * spe * sp;
                }
            }
        }
        __syncthreads();
        // online softmax update (16 lanes per row)
        {
            int r = t >> 4, c = t & 15;
            float* sp = &s_s[r * 128 + c * 8];
            float e[8];
            float lm = -INFINITY;
#pragma unroll
            for (int u = 0; u < 8; u++) { e[u] = sp[u]; lm = fmaxf(lm, e[u]); }
#pragma unroll
            for (int m = 8; m; m >>= 1) lm = fmaxf(lm, __shfl_xor(lm, m, 64));
            float mold = m_s[r];
            float mnew = fmaxf(mold, lm);
            float fct = expf(mold - mnew);   // exp(-inf)=0 on first tile
            float ps = 0.f;
#pragma unroll
            for (int u = 0; u < 8; u++) {
                float p = expf(e[u] - mnew);
                sp[u] = p;
                ps += p;
            }
#pragma unroll
            for (int m = 8; m; m >>= 1) ps += __shfl_xor(ps, m, 64);
            if (c == 0) {
                m_s[r] = mnew;
                f_s[r] = fct;
                l_s[r] = l_s[r] * fct + ps;
            }
        }
        __syncthreads();
        // PV: 8 rows x 2 d per thread over 32 j
        {
#pragma unroll
            for (int rr = 0; rr < 8; rr++) {
                float fct = f_s[rbaseP + rr];
                accO[rr][0] *= fct;
                accO[rr][1] *= fct;
            }
            const float2* v_s2 = (const float2*)v_s4;
            for (int jj = 0; jj < 32; jj++) {
                int j = part * 32 + jj;
                float2 vv = v_s2[j * 32 + (t & 31)];
#pragma unroll
                for (int rr = 0; rr < 8; rr++) {
                    float p = s_s[(rbaseP + rr) * 128 + j];
                    accO[rr][0] = fmaf(p, vv.x, accO[rr][0]);
                    accO[rr][1] = fmaf(p, vv.y, accO[rr][1]);
                }
            }
        }
    }
    __syncthreads();
    // cross-part reduction through LDS (reuse k_s4 space)
    float* red = (float*)k_s4;   // [part][16][64]
#pragma unroll
    for (int rr = 0; rr < 8; rr++) {
        red[(part * 16 + rbaseP + rr) * 64 + dbase] = accO[rr][0];
        red[(part * 16 + rbaseP + rr) * 64 + dbase + 1] = accO[rr][1];
    }
    __syncthreads();
#pragma unroll
    for (int oo = 0; oo < 4; oo++) {
        int o = t + 256 * oo;
        int r = o >> 6, d = o & 63;
        float s = red[r * 64 + d] + red[(16 + r) * 64 + d] + red[(32 + r) * 64 + d] + red[(48 + r) * 64 + d];
        attn_out[(b * N + i0 + r) * INNER + h * DH + d] = s / l_s[r];
    }
}

// ---------------- LN + GELU + out proj ----------------
__global__ __launch_bounds__(256) void k_out(const float* __restrict__ aout, const float* __restrict__ g,
                                             const float* __restrict__ be, const float* __restrict__ Wout,
                                             const float* __restrict__ bout, float* __restrict__ out) {
    __shared__ float y_s[512];
    __shared__ float red[256];
    __shared__ float stats[2];
    int t = threadIdx.x;
    int b = blockIdx.x >> 10, i = blockIdx.x & 1023;
    const float* row = aout + (b * N + i) * INNER;
    float v0 = row[t], v1 = row[t + 256];
    y_s[t] = v0;
    y_s[t + 256] = v1;
    float s1 = v0 + v1, s2 = v0 * v0 + v1 * v1;
#pragma unroll
    for (int m = 32; m; m >>= 1) {
        s1 += __shfl_xor(s1, m, 64);
        s2 += __shfl_xor(s2, m, 64);
    }
    if ((t & 63) == 0) {
        red[t >> 6] = s1;
        red[4 + (t >> 6)] = s2;
    }
    __syncthreads();
    if (t == 0) {
        float S1 = red[0] + red[1] + red[2] + red[3];
        float S2 = red[4] + red[5] + red[6] + red[7];
        float mean = S1 * (1.f / 512.f);
        float var = S2 * (1.f / 512.f) - mean * mean;
        stats[0] = mean;
        stats[1] = rsqrtf(var + 1e-5f);
    }
    __syncthreads();
    float mean = stats[0], rstd = stats[1];
#pragma unroll
    for (int k = 0; k < 2; k++) {
        int c = t + 256 * k;
        float xv = (k == 0) ? v0 : v1;
        float yn = g[c] * (xv - mean) * rstd + be[c];
        y_s[c] = 0.5f * yn * (1.f + erff(yn * 0.70710678118f));
    }
    __syncthreads();
    int o = t & 63, prt = t >> 6;
    float acc = 0.f;
    for (int c = prt * 128; c < prt * 128 + 128; c++) acc = fmaf(y_s[c], Wout[c * 64 + o], acc);
    red[t] = acc;
    __syncthreads();
    if (t < 64) {
        float val = red[t] + red[t + 64] + red[t + 128] + red[t + 192] + bout[t];
        out[(b * N + i) * 64 + t] = val;
    }
}

extern "C" void kernel_launch(void* const* d_in, const int* in_sizes, int n_in,
                              void* d_out, int out_size, void* d_ws, size_t ws_size,
                              hipStream_t stream) {
    const float* x = (const float*)d_in[0];
    const float* Wqkv = (const float*)d_in[1];
    const float* bqkv = (const float*)d_in[2];
    const float* lng = (const float*)d_in[3];
    const float* lnb = (const float*)d_in[4];
    const float* Wout = (const float*)d_in[5];
    const float* bout = (const float*)d_in[6];
    float* out = (float*)d_out;

    float* ws = (float*)d_ws;
    size_t off = 0;
    float* xT = ws + off;   off += (size_t)B * D * N;       // 262144
    float* sq = ws + off;   off += (size_t)B * N;           // 4096
    float* scal = ws + off; off += 16;                      // [0]=sig_sum [1]=w_sum
    float* spa = ws + off;  off += (size_t)N * N;           // 1M
    float* qe = ws + off;   off += (size_t)B * H * N * DH;  // 2M
    float* ke = ws + off;   off += (size_t)B * H * N * DH;  // 2M
    float* vv = ws + off;   off += (size_t)B * H * N * DH;  // 2M
    float* wbuf = ws + off; off += (size_t)B * N * N;       // 4M
    float* aout = ws + off; off += (size_t)B * N * INNER;   // 2M
    // total ~13.9M floats = ~53 MB of ws

    // spa sigma/mu computed exactly on host via coordinate-delta histogram
    // (input-independent; runs only at capture time)
    double ssum = 0.0;
    const double cnt = (double)N * (double)N;
    for (int dx = -15; dx <= 15; dx++)
        for (int dy = -15; dy <= 15; dy++)
            for (int dz = -3; dz <= 3; dz++) {
                double c = (double)(16 - abs(dx)) * (double)(16 - abs(dy)) * (double)(4 - abs(dz));
                double d2 = (double)(dx * dx + dy * dy + dz * dz);
                ssum += c * sqrt(d2);
            }
    double sigma = ssum / cnt;
    double inv2s2 = 1.0 / (2.0 * sigma * sigma);
    double wsum = 0.0;
    for (int dx = -15; dx <= 15; dx++)
        for (int dy = -15; dy <= 15; dy++)
            for (int dz = -3; dz <= 3; dz++) {
                double c = (double)(16 - abs(dx)) * (double)(16 - abs(dy)) * (double)(4 - abs(dz));
                double d2 = (double)(dx * dx + dy * dy + dz * dz);
                wsum += c * exp(-d2 * inv2s2);
            }
    double mu = wsum / cnt;

    hipMemsetAsync(scal, 0, 16 * sizeof(float), stream);
    k_prep<<<B * N, 64, 0, stream>>>(x, xT, sq);
    k_spa<<<(N * N) / 1024, 256, 0, stream>>>(spa, (float)inv2s2, (float)mu);
    k_qkv<<<(B * N) / 8, 256, 0, stream>>>(x, Wqkv, bqkv, qe, ke, vv);
    k_gram<<<dim3(N / 16, B), 256, 0, stream>>>(x, xT, sq, wbuf, scal);
    k_wexp<<<4096, 256, 0, stream>>>(wbuf, scal, scal + 1);
    k_attn<<<dim3(N / 16, H, B), 256, 0, stream>>>(qe, ke, vv, wbuf, spa, scal + 1, aout);
    k_out<<<B * N, 256, 0, stream>>>(aout, lng, lnb, Wout, bout, out);
}

// Round 2
// 354.514 us; speedup vs baseline: 1.5250x; 1.5250x over previous
//
#include <hip/hip_runtime.h>
#include <math.h>
#include <stdlib.h>

#define B 4
#define N 1024
#define D 64
#define H 8
#define DH 64
#define INNER 512
#define C3 1536

typedef __attribute__((ext_vector_type(8))) short bf16x8;
typedef __attribute__((ext_vector_type(4))) float f32x4;

__device__ inline short f2bf(float f) {
    unsigned u = __builtin_bit_cast(unsigned, f);
    unsigned r = (u + 0x7FFFu + ((u >> 16) & 1u)) >> 16;
    return (short)r;
}
__device__ inline float bf2f(short s) {
    return __builtin_bit_cast(float, ((unsigned)(unsigned short)s) << 16);
}

// ---------------- prep: xT and row sumsq ----------------
__global__ void k_prep(const float* __restrict__ x, float* __restrict__ xT, float* __restrict__ sq) {
    int b = blockIdx.x >> 10, i = blockIdx.x & 1023, t = threadIdx.x; // 64 threads
    float v = x[(b * N + i) * D + t];
    xT[(b * D + t) * N + i] = v;
    float s = v * v;
#pragma unroll
    for (int m = 32; m; m >>= 1) s += __shfl_xor(s, m, 64);
    if (t == 0) sq[b * N + i] = s;
}

// ---------------- spa: constant grid Gaussian, thresholded ----------------
__global__ void k_spa(float* __restrict__ spa, float inv2s2, float mu) {
    int flat4 = blockIdx.x * 256 + threadIdx.x;   // 0..262143 (f4 units)
    int i = flat4 >> 8;
    int j0 = (flat4 & 255) * 4;
    int ix = i >> 6, iy = (i >> 2) & 15, iz = i & 3;
    float4 o;
    float* op = (float*)&o;
#pragma unroll
    for (int jj = 0; jj < 4; jj++) {
        int j = j0 + jj;
        int jx = j >> 6, jy = (j >> 2) & 15, jz = j & 3;
        float d2 = (float)((ix - jx) * (ix - jx) + (iy - jy) * (iy - jy) + (iz - jz) * (iz - jz));
        float w = expf(-d2 * inv2s2);
        op[jj] = (w < mu) ? 0.f : w;
    }
    ((float4*)spa)[flat4] = o;
}

// ---------------- qkv: x @ W_qkv + b, elu+1 on q/k, bf16 split outputs + vT ----------------
__global__ __launch_bounds__(256) void k_qkv(const float* __restrict__ x, const float* __restrict__ Wqkv,
                                             const float* __restrict__ bqkv,
                                             short* __restrict__ qeh, short* __restrict__ qel,
                                             short* __restrict__ keh, short* __restrict__ kel,
                                             short* __restrict__ vT) {
    __shared__ float x_s[8 * 64];
    __shared__ short v_lds[8 * 512];
    int t = threadIdx.x;
    int b = blockIdx.x >> 7;
    int i0 = (blockIdx.x & 127) * 8;
#pragma unroll
    for (int k = 0; k < 2; k++) {
        int idx = t + 256 * k;
        x_s[idx] = x[(b * N + i0 + (idx >> 6)) * D + (idx & 63)];
    }
    __syncthreads();
    const float4* x_s4 = (const float4*)x_s;
#pragma unroll
    for (int ci = 0; ci < 6; ci++) {
        int c = ci * 256 + t;
        float bias = bqkv[c];
        float acc[8];
#pragma unroll
        for (int r = 0; r < 8; r++) acc[r] = bias;
        for (int d4 = 0; d4 < 16; d4++) {
            int d = d4 * 4;
            float w0 = Wqkv[(d + 0) * C3 + c];
            float w1 = Wqkv[(d + 1) * C3 + c];
            float w2 = Wqkv[(d + 2) * C3 + c];
            float w3 = Wqkv[(d + 3) * C3 + c];
#pragma unroll
            for (int r = 0; r < 8; r++) {
                float4 xv = x_s4[r * 16 + d4];
                acc[r] = fmaf(xv.x, w0, acc[r]);
                acc[r] = fmaf(xv.y, w1, acc[r]);
                acc[r] = fmaf(xv.z, w2, acc[r]);
                acc[r] = fmaf(xv.w, w3, acc[r]);
            }
        }
        int seg = c >> 9;       // 0=q 1=k 2=v
        int cc = c & 511;
        int hh = cc >> 6, dh = cc & 63;
        int bh = b * H + hh;
#pragma unroll
        for (int r = 0; r < 8; r++) {
            float val = acc[r];
            int off = (bh * N + (i0 + r)) * DH + dh;
            if (seg == 0) {
                float a = val > 0.f ? val + 1.f : __expf(val);
                short hs = f2bf(a);
                qeh[off] = hs;
                qel[off] = f2bf(a - bf2f(hs));
            } else if (seg == 1) {
                float a = val > 0.f ? val + 1.f : __expf(val);
                short hs = f2bf(a);
                keh[off] = hs;
                kel[off] = f2bf(a - bf2f(hs));
            } else {
                v_lds[r * 512 + cc] = f2bf(val);
            }
        }
    }
    __syncthreads();
    // vT writeout: vT[bh*64+dh][n] bf16, 16B per thread-row
#pragma unroll
    for (int rep = 0; rep < 2; rep++) {
        int cc = t + 256 * rep;
        int hh = cc >> 6, dh = cc & 63;
        short tmp[8];
#pragma unroll
        for (int r = 0; r < 8; r++) tmp[r] = v_lds[r * 512 + cc];
        ((bf16x8*)vT)[((b * H + hh) * 64 + dh) * (N / 8) + (i0 >> 3)] = *(bf16x8*)tmp;
    }
}

// ---------------- gram: d2 = sqi + sqj - 2 x.x^T, + sum of dist ----------------
__global__ __launch_bounds__(256) void k_gram(const float* __restrict__ x, const float* __restrict__ xT,
                                              const float* __restrict__ sq, float* __restrict__ w,
                                              float* __restrict__ d_sig) {
    __shared__ float xi_s[16 * 64];
    __shared__ float sqi_s[16];
    __shared__ float red[4];
    int t = threadIdx.x;
    int b = blockIdx.y;
    int i0 = blockIdx.x * 16;
#pragma unroll
    for (int k = 0; k < 4; k++) {
        int idx = t + 256 * k;
        xi_s[idx] = x[(b * N + i0 + (idx >> 6)) * D + (idx & 63)];
    }
    if (t < 16) sqi_s[t] = sq[b * N + i0 + t];
    __syncthreads();
    const float4* xi_s4 = (const float4*)xi_s;
    float part = 0.f;
    for (int jt = 0; jt < 4; jt++) {
        int j = jt * 256 + t;
        float acc[16];
#pragma unroll
        for (int r = 0; r < 16; r++) acc[r] = 0.f;
        for (int d4 = 0; d4 < 16; d4++) {
            int d = d4 * 4;
            float v0 = xT[(b * D + d + 0) * N + j];
            float v1 = xT[(b * D + d + 1) * N + j];
            float v2 = xT[(b * D + d + 2) * N + j];
            float v3 = xT[(b * D + d + 3) * N + j];
#pragma unroll
            for (int r = 0; r < 16; r++) {
                float4 xi = xi_s4[r * 16 + d4];
                acc[r] = fmaf(xi.x, v0, acc[r]);
                acc[r] = fmaf(xi.y, v1, acc[r]);
                acc[r] = fmaf(xi.z, v2, acc[r]);
                acc[r] = fmaf(xi.w, v3, acc[r]);
            }
        }
        float sqj = sq[b * N + j];
#pragma unroll
        for (int r = 0; r < 16; r++) {
            float d2 = sqi_s[r] + sqj - 2.f * acc[r];
            d2 = fmaxf(d2, 0.f);
            w[(b * N + i0 + r) * N + j] = d2;
            part += (d2 > 1e-12f) ? sqrtf(d2) : 0.f;
        }
    }
#pragma unroll
    for (int m = 32; m; m >>= 1) part += __shfl_xor(part, m, 64);
    if ((t & 63) == 0) red[t >> 6] = part;
    __syncthreads();
    if (t == 0) atomicAdd(d_sig, red[0] + red[1] + red[2] + red[3]);
}

// ---------------- wexp: w = exp(-d2/(2 sigma^2)), + sum w ----------------
__global__ __launch_bounds__(256) void k_wexp(float* __restrict__ w, const float* __restrict__ d_sig,
                                              float* __restrict__ d_wsum) {
    __shared__ float red[4];
    int idx = blockIdx.x * 256 + threadIdx.x;      // f4 index, 1048576 total
    float sigma = d_sig[0] * (1.f / 4194304.f);
    float inv = 1.f / (2.f * sigma * sigma);
    float4 v = ((float4*)w)[idx];
    v.x = expf(-v.x * inv);
    v.y = expf(-v.y * inv);
    v.z = expf(-v.z * inv);
    v.w = expf(-v.w * inv);
    ((float4*)w)[idx] = v;
    float s = v.x + v.y + v.z + v.w;
#pragma unroll
    for (int m = 32; m; m >>= 1) s += __shfl_xor(s, m, 64);
    if ((threadIdx.x & 63) == 0) red[threadIdx.x >> 6] = s;
    __syncthreads();
    if (threadIdx.x == 0) atomicAdd(d_wsum, red[0] + red[1] + red[2] + red[3]);
}

// ---------------- attention: MFMA flash, 4 waves x 16 rows, 64-wide j tiles ----------------
__global__ __launch_bounds__(256) void k_attn(
    const short* __restrict__ qeh, const short* __restrict__ qel,
    const short* __restrict__ keh, const short* __restrict__ kel,
    const short* __restrict__ vT,
    const float* __restrict__ w, const float* __restrict__ spa,
    const float* __restrict__ d_wsum, float* __restrict__ aout) {
    __shared__ short Kh[64 * 64];   // [j][d] swizzled 16B slots: slot^=(j&7)
    __shared__ short Kl[64 * 64];
    __shared__ short Vt[64 * 64];   // [d][j] swizzled
    __shared__ short P[4][16 * 64]; // per wave [row][j] swizzled
    int t = threadIdx.x;
    int wv = t >> 6, lane = t & 63, l4 = lane & 15, g = lane >> 4;
    int i0 = blockIdx.x * 64;
    int h = blockIdx.y, b = blockIdx.z, bh = b * H + h;
    float mu = d_wsum[0] * (1.f / 4194304.f);
    int irow = i0 + wv * 16;

    // Q fragments (A-operand): row = irow + l4, k = 8g+e+32*mk
    bf16x8 qh[2], ql[2];
    {
        const bf16x8* qh8 = (const bf16x8*)qeh;
        const bf16x8* ql8 = (const bf16x8*)qel;
        int base = (bh * N + irow + l4) * 8 + g;
#pragma unroll
        for (int mk = 0; mk < 2; mk++) {
            qh[mk] = qh8[base + 4 * mk];
            ql[mk] = ql8[base + 4 * mk];
        }
    }
    f32x4 O[4];
#pragma unroll
    for (int dt = 0; dt < 4; dt++) O[dt] = f32x4{0.f, 0.f, 0.f, 0.f};
    float m_r[4] = {-INFINITY, -INFINITY, -INFINITY, -INFINITY};
    float l_r[4] = {0.f, 0.f, 0.f, 0.f};

    const bf16x8* Kh8 = (const bf16x8*)Kh;
    const bf16x8* Kl8 = (const bf16x8*)Kl;
    const bf16x8* Vt8 = (const bf16x8*)Vt;

    for (int tile = 0; tile < 16; ++tile) {
        int j0 = tile * 64;
        __syncthreads();
        // stage Kh, Kl, Vt (swizzled)
        {
            const bf16x8* kh8 = (const bf16x8*)keh;
            const bf16x8* kl8 = (const bf16x8*)kel;
            const bf16x8* v8 = (const bf16x8*)vT;
            bf16x8* KhW = (bf16x8*)Kh;
            bf16x8* KlW = (bf16x8*)Kl;
            bf16x8* VtW = (bf16x8*)Vt;
#pragma unroll
            for (int rep = 0; rep < 2; rep++) {
                int c = t + 256 * rep;       // 0..511
                int j = c >> 3, s = c & 7;
                KhW[j * 8 + (s ^ (j & 7))] = kh8[(bh * N + j0 + j) * 8 + s];
                KlW[j * 8 + (s ^ (j & 7))] = kl8[(bh * N + j0 + j) * 8 + s];
                VtW[j * 8 + (s ^ (j & 7))] = v8[(bh * 64 + j) * (N / 8) + (j0 >> 3) + s];
            }
        }
        __syncthreads();
        // QK^T: 4 col-tiles of 16, split-bf16 (hh + lh + hl)
        f32x4 sc[4];
#pragma unroll
        for (int ct = 0; ct < 4; ct++) {
            int j = 16 * ct + l4;
            int sw = j & 7;
            bf16x8 kh0 = Kh8[j * 8 + ((g) ^ sw)];
            bf16x8 kh1 = Kh8[j * 8 + ((4 + g) ^ sw)];
            bf16x8 kl0 = Kl8[j * 8 + ((g) ^ sw)];
            bf16x8 kl1 = Kl8[j * 8 + ((4 + g) ^ sw)];
            f32x4 a = f32x4{0.f, 0.f, 0.f, 0.f};
            a = __builtin_amdgcn_mfma_f32_16x16x32_bf16(qh[0], kh0, a, 0, 0, 0);
            a = __builtin_amdgcn_mfma_f32_16x16x32_bf16(qh[1], kh1, a, 0, 0, 0);
            a = __builtin_amdgcn_mfma_f32_16x16x32_bf16(ql[0], kh0, a, 0, 0, 0);
            a = __builtin_amdgcn_mfma_f32_16x16x32_bf16(ql[1], kh1, a, 0, 0, 0);
            a = __builtin_amdgcn_mfma_f32_16x16x32_bf16(qh[0], kl0, a, 0, 0, 0);
            a = __builtin_amdgcn_mfma_f32_16x16x32_bf16(qh[1], kl1, a, 0, 0, 0);
            sc[ct] = a;
        }
        // mask + online softmax (row = irow + 4g + r, col = j0 + 16ct + l4)
        float p[4][4];
        float fr[4];
#pragma unroll
        for (int r = 0; r < 4; r++) {
            int i = irow + 4 * g + r;
            float mx = -INFINITY;
#pragma unroll
            for (int ct = 0; ct < 4; ct++) {
                int jg = j0 + 16 * ct + l4;
                float wv_ = w[(b * N + i) * N + jg];
                float sp = spa[i * N + jg];
                float spe = (wv_ < mu) ? 0.f : wv_;
                float val = sc[ct][r] * 0.125f * spe * sp;
                p[ct][r] = val;
                mx = fmaxf(mx, val);
            }
#pragma unroll
            for (int msk = 1; msk < 16; msk <<= 1) mx = fmaxf(mx, __shfl_xor(mx, msk, 64));
            float mo = m_r[r];
            float mn = fmaxf(mo, mx);
            float f = __expf(mo - mn);
            float s = 0.f;
#pragma unroll
            for (int ct = 0; ct < 4; ct++) {
                float e = __expf(p[ct][r] - mn);
                p[ct][r] = e;
                s += e;
            }
#pragma unroll
            for (int msk = 1; msk < 16; msk <<= 1) s += __shfl_xor(s, msk, 64);
            l_r[r] = l_r[r] * f + s;
            m_r[r] = mn;
            fr[r] = f;
        }
        // rescale O
#pragma unroll
        for (int dt = 0; dt < 4; dt++) {
            O[dt][0] *= fr[0];
            O[dt][1] *= fr[1];
            O[dt][2] *= fr[2];
            O[dt][3] *= fr[3];
        }
        // write P (bf16, swizzled) : row=4g+r, byte slot = (l4>>3)+2ct
        short* Pw = P[wv];
#pragma unroll
        for (int ct = 0; ct < 4; ct++) {
#pragma unroll
            for (int r = 0; r < 4; r++) {
                int row = 4 * g + r;
                int slot = ((l4 >> 3) + 2 * ct) ^ (row & 7);
                Pw[row * 64 + slot * 8 + (l4 & 7)] = f2bf(p[ct][r]);
            }
        }
        // PV: A = P (row=l4, k=8g+e+32ks), B = Vt (col=l4+16dt)
        const bf16x8* Pr = (const bf16x8*)P[wv];
#pragma unroll
        for (int ks = 0; ks < 2; ks++) {
            bf16x8 pa = Pr[l4 * 8 + ((g + 4 * ks) ^ (l4 & 7))];
#pragma unroll
            for (int dt = 0; dt < 4; dt++) {
                int d = l4 + 16 * dt;
                bf16x8 bv = Vt8[d * 8 + ((g + 4 * ks) ^ (d & 7))];
                O[dt] = __builtin_amdgcn_mfma_f32_16x16x32_bf16(pa, bv, O[dt], 0, 0, 0);
            }
        }
    }
    // epilogue
#pragma unroll
    for (int dt = 0; dt < 4; dt++) {
#pragma unroll
        for (int r = 0; r < 4; r++) {
            int i = irow + 4 * g + r;
            aout[(b * N + i) * INNER + h * 64 + l4 + 16 * dt] = O[dt][r] / l_r[r];
        }
    }
}

// ---------------- LN + GELU + out proj ----------------
__global__ __launch_bounds__(256) void k_out(const float* __restrict__ aout, const float* __restrict__ g,
                                             const float* __restrict__ be, const float* __restrict__ Wout,
                                             const float* __restrict__ bout, float* __restrict__ out) {
    __shared__ float y_s[512];
    __shared__ float red[256];
    __shared__ float stats[2];
    int t = threadIdx.x;
    int b = blockIdx.x >> 10, i = blockIdx.x & 1023;
    const float* row = aout + (b * N + i) * INNER;
    float v0 = row[t], v1 = row[t + 256];
    y_s[t] = v0;
    y_s[t + 256] = v1;
    float s1 = v0 + v1, s2 = v0 * v0 + v1 * v1;
#pragma unroll
    for (int m = 32; m; m >>= 1) {
        s1 += __shfl_xor(s1, m, 64);
        s2 += __shfl_xor(s2, m, 64);
    }
    if ((t & 63) == 0) {
        red[t >> 6] = s1;
        red[4 + (t >> 6)] = s2;
    }
    __syncthreads();
    if (t == 0) {
        float S1 = red[0] + red[1] + red[2] + red[3];
        float S2 = red[4] + red[5] + red[6] + red[7];
        float mean = S1 * (1.f / 512.f);
        float var = S2 * (1.f / 512.f) - mean * mean;
        stats[0] = mean;
        stats[1] = rsqrtf(var + 1e-5f);
    }
    __syncthreads();
    float mean = stats[0], rstd = stats[1];
#pragma unroll
    for (int k = 0; k < 2; k++) {
        int c = t + 256 * k;
        float xv = (k == 0) ? v0 : v1;
        float yn = g[c] * (xv - mean) * rstd + be[c];
        y_s[c] = 0.5f * yn * (1.f + erff(yn * 0.70710678118f));
    }
    __syncthreads();
    int o = t & 63, prt = t >> 6;
    float acc = 0.f;
    for (int c = prt * 128; c < prt * 128 + 128; c++) acc = fmaf(y_s[c], Wout[c * 64 + o], acc);
    red[t] = acc;
    __syncthreads();
    if (t < 64) {
        float val = red[t] + red[t + 64] + red[t + 128] + red[t + 192] + bout[t];
        out[(b * N + i) * 64 + t] = val;
    }
}

extern "C" void kernel_launch(void* const* d_in, const int* in_sizes, int n_in,
                              void* d_out, int out_size, void* d_ws, size_t ws_size,
                              hipStream_t stream) {
    const float* x = (const float*)d_in[0];
    const float* Wqkv = (const float*)d_in[1];
    const float* bqkv = (const float*)d_in[2];
    const float* lng = (const float*)d_in[3];
    const float* lnb = (const float*)d_in[4];
    const float* Wout = (const float*)d_in[5];
    const float* bout = (const float*)d_in[6];
    float* out = (float*)d_out;

    float* ws = (float*)d_ws;
    size_t off = 0;
    float* xT = ws + off;   off += (size_t)B * D * N;       // 262144
    float* sq = ws + off;   off += (size_t)B * N;           // 4096
    float* scal = ws + off; off += 16;
    float* spa = ws + off;  off += (size_t)N * N;           // 1M
    float* wbuf = ws + off; off += (size_t)B * N * N;       // 4M
    float* aout = ws + off; off += (size_t)B * N * INNER;   // 2M
    short* sbase = (short*)(ws + off);
    size_t soff = 0;
    short* qeh = sbase + soff; soff += (size_t)B * H * N * DH;   // 2M shorts each
    short* qel = sbase + soff; soff += (size_t)B * H * N * DH;
    short* keh = sbase + soff; soff += (size_t)B * H * N * DH;
    short* kel = sbase + soff; soff += (size_t)B * H * N * DH;
    short* vT  = sbase + soff; soff += (size_t)B * H * N * DH;
    // total: ~29 MB f32 + 21 MB bf16 = ~50 MB

    // spa sigma/mu on host (input-independent)
    double ssum = 0.0;
    const double cnt = (double)N * (double)N;
    for (int dx = -15; dx <= 15; dx++)
        for (int dy = -15; dy <= 15; dy++)
            for (int dz = -3; dz <= 3; dz++) {
                double c = (double)(16 - abs(dx)) * (double)(16 - abs(dy)) * (double)(4 - abs(dz));
                double d2 = (double)(dx * dx + dy * dy + dz * dz);
                ssum += c * sqrt(d2);
            }
    double sigma = ssum / cnt;
    double inv2s2 = 1.0 / (2.0 * sigma * sigma);
    double wsum = 0.0;
    for (int dx = -15; dx <= 15; dx++)
        for (int dy = -15; dy <= 15; dy++)
            for (int dz = -3; dz <= 3; dz++) {
                double c = (double)(16 - abs(dx)) * (double)(16 - abs(dy)) * (double)(4 - abs(dz));
                double d2 = (double)(dx * dx + dy * dy + dz * dz);
                wsum += c * exp(-d2 * inv2s2);
            }
    double mu = wsum / cnt;

    hipMemsetAsync(scal, 0, 16 * sizeof(float), stream);
    k_prep<<<B * N, 64, 0, stream>>>(x, xT, sq);
    k_spa<<<(N * N) / 1024, 256, 0, stream>>>(spa, (float)inv2s2, (float)mu);
    k_qkv<<<(B * N) / 8, 256, 0, stream>>>(x, Wqkv, bqkv, qeh, qel, keh, kel, vT);
    k_gram<<<dim3(N / 16, B), 256, 0, stream>>>(x, xT, sq, wbuf, scal);
    k_wexp<<<4096, 256, 0, stream>>>(wbuf, scal, scal + 1);
    k_attn<<<dim3(N / 64, H, B), 256, 0, stream>>>(qeh, qel, keh, kel, vT, wbuf, spa, scal + 1, aout);
    k_out<<<B * N, 256, 0, stream>>>(aout, lng, lnb, Wout, bout, out);
}

// Round 4
// 263.755 us; speedup vs baseline: 2.0498x; 1.3441x over previous
//
#include <hip/hip_runtime.h>
#include <math.h>
#include <stdlib.h>

#define B 4
#define N 1024
#define D 64
#define H 8
#define DH 64
#define INNER 512
#define C3 1536

typedef __attribute__((ext_vector_type(8))) short bf16x8;
typedef __attribute__((ext_vector_type(4))) float f32x4;

__device__ inline short f2bf(float f) {
    unsigned u = __builtin_bit_cast(unsigned, f);
    unsigned r = (u + 0x7FFFu + ((u >> 16) & 1u)) >> 16;
    return (short)r;
}
__device__ inline float bf2f(short s) {
    return __builtin_bit_cast(float, ((unsigned)(unsigned short)s) << 16);
}

// ---------------- conv: x -> xh/xl + sq ; Wqkv -> Wh/Wl transposed [c][d] ----------------
__global__ __launch_bounds__(256) void k_conv(const float* __restrict__ x, const float* __restrict__ Wqkv,
                                              short* __restrict__ xh, short* __restrict__ xl,
                                              float* __restrict__ sq,
                                              short* __restrict__ Wh, short* __restrict__ Wl) {
    __shared__ float lds[64 * 65];
    int t = threadIdx.x;
    if (blockIdx.x < 1024) {
        int i = blockIdx.x * 4 + (t >> 6), d = t & 63;
        float v = x[i * 64 + d];
        short hs = f2bf(v);
        xh[i * 64 + d] = hs;
        xl[i * 64 + d] = f2bf(v - bf2f(hs));
        float s = v * v;
#pragma unroll
        for (int m = 32; m; m >>= 1) s += __shfl_xor(s, m, 64);
        if (d == 0) sq[i] = s;
    } else {
        int c0 = (blockIdx.x - 1024) * 64;
#pragma unroll
        for (int it = 0; it < 16; it++) {
            int d = it * 4 + (t >> 6), cl = t & 63;
            lds[cl * 65 + d] = Wqkv[d * C3 + c0 + cl];
        }
        __syncthreads();
#pragma unroll
        for (int it = 0; it < 16; it++) {
            int cl = it * 4 + (t >> 6), d = t & 63;
            float v = lds[cl * 65 + d];
            short hs = f2bf(v);
            Wh[(c0 + cl) * 64 + d] = hs;
            Wl[(c0 + cl) * 64 + d] = f2bf(v - bf2f(hs));
        }
    }
}

// ---------------- spa: constant grid Gaussian, thresholded ----------------
__global__ void k_spa(float* __restrict__ spa, float inv2s2, float mu) {
    int flat4 = blockIdx.x * 256 + threadIdx.x;
    int i = flat4 >> 8;
    int j0 = (flat4 & 255) * 4;
    int ix = i >> 6, iy = (i >> 2) & 15, iz = i & 3;
    float4 o;
    float* op = (float*)&o;
#pragma unroll
    for (int jj = 0; jj < 4; jj++) {
        int j = j0 + jj;
        int jx = j >> 6, jy = (j >> 2) & 15, jz = j & 3;
        float d2 = (float)((ix - jx) * (ix - jx) + (iy - jy) * (iy - jy) + (iz - jz) * (iz - jz));
        float w = expf(-d2 * inv2s2);
        op[jj] = (w < mu) ? 0.f : w;
    }
    ((float4*)spa)[flat4] = o;
}

// ---------------- qkv GEMM on MFMA: [4096 x 1536] = x[4096x64] @ W[64x1536] ----------------
__global__ __launch_bounds__(256) void k_qkvm(
    const short* __restrict__ xh, const short* __restrict__ xl,
    const short* __restrict__ Wh, const short* __restrict__ Wl,
    const float* __restrict__ bqkv,
    short* __restrict__ qeh, short* __restrict__ qel,
    short* __restrict__ keh, short* __restrict__ kel,
    short* __restrict__ vT) {
    __shared__ short vt_lds[128 * 66];   // [c_local][row] padded
    int t = threadIdx.x;
    int wv = t >> 6, lane = t & 63, l4 = lane & 15, g = lane >> 4;
    int i0 = blockIdx.x * 64;            // global row (0..4095)
    int c0 = blockIdx.y * 128;           // col
    int irow = i0 + wv * 16;
    const bf16x8* xh8 = (const bf16x8*)xh;
    const bf16x8* xl8 = (const bf16x8*)xl;
    const bf16x8* Wh8 = (const bf16x8*)Wh;
    const bf16x8* Wl8 = (const bf16x8*)Wl;

    int abase = (irow + l4) * 8 + g;
    bf16x8 ah[2], al[2];
    ah[0] = xh8[abase];
    ah[1] = xh8[abase + 4];
    al[0] = xl8[abase];
    al[1] = xl8[abase + 4];

    f32x4 acc[8];
#pragma unroll
    for (int ct = 0; ct < 8; ct++) acc[ct] = f32x4{0.f, 0.f, 0.f, 0.f};
#pragma unroll
    for (int ct = 0; ct < 8; ct++) {
        int c = c0 + 16 * ct + l4;
        int bbase = c * 8 + g;
        bf16x8 bh0 = Wh8[bbase], bh1 = Wh8[bbase + 4];
        bf16x8 bl0 = Wl8[bbase], bl1 = Wl8[bbase + 4];
        f32x4 a = acc[ct];
        a = __builtin_amdgcn_mfma_f32_16x16x32_bf16(ah[0], bh0, a, 0, 0, 0);
        a = __builtin_amdgcn_mfma_f32_16x16x32_bf16(ah[1], bh1, a, 0, 0, 0);
        a = __builtin_amdgcn_mfma_f32_16x16x32_bf16(al[0], bh0, a, 0, 0, 0);
        a = __builtin_amdgcn_mfma_f32_16x16x32_bf16(al[1], bh1, a, 0, 0, 0);
        a = __builtin_amdgcn_mfma_f32_16x16x32_bf16(ah[0], bl0, a, 0, 0, 0);
        a = __builtin_amdgcn_mfma_f32_16x16x32_bf16(ah[1], bl1, a, 0, 0, 0);
        acc[ct] = a;
    }
    int seg = c0 >> 9;   // block-uniform: 0=q 1=k 2=v
#pragma unroll
    for (int ct = 0; ct < 8; ct++) {
        int c = c0 + 16 * ct + l4;
        float bias = bqkv[c];
        int cc = c & 511, hh = cc >> 6, dh = cc & 63;
#pragma unroll
        for (int r = 0; r < 4; r++) {
            int i_e = irow + 4 * g + r;
            int b = i_e >> 10, i = i_e & 1023;
            float val = acc[ct][r] + bias;
            if (seg < 2) {
                float a_ = val > 0.f ? val + 1.f : __expf(val);
                short hs = f2bf(a_);
                short ls = f2bf(a_ - bf2f(hs));
                int off = ((b * H + hh) * N + i) * 64 + dh;
                if (seg == 0) { qeh[off] = hs; qel[off] = ls; }
                else          { keh[off] = hs; kel[off] = ls; }
            } else {
                vt_lds[(16 * ct + l4) * 66 + (wv * 16 + 4 * g + r)] = f2bf(val);
            }
        }
    }
    if (seg == 2) {
        __syncthreads();
        int b = i0 >> 10, ib = i0 & 1023;
#pragma unroll
        for (int it = 0; it < 4; it++) {
            int idx = t + 256 * it;      // 1024 chunks: 128 cols x 8 row-chunks
            int cl = idx >> 3, i8 = idx & 7;
            short tmp[8];
#pragma unroll
            for (int r8 = 0; r8 < 8; r8++) tmp[r8] = vt_lds[cl * 66 + i8 * 8 + r8];
            int cc = (c0 + cl) & 511, hh = cc >> 6, dh = cc & 63;
            ((bf16x8*)vT)[((b * H + hh) * 64 + dh) * (N / 8) + (ib >> 3) + i8] = *(bf16x8*)tmp;
        }
    }
}

// ---------------- gram on MFMA: d2 = sqi + sqj - 2 x.x^T, + sum dist ----------------
__global__ __launch_bounds__(256) void k_gramm(
    const short* __restrict__ xh, const short* __restrict__ xl,
    const float* __restrict__ sq, float* __restrict__ w, float* __restrict__ d_sig) {
    __shared__ float red[4];
    int t = threadIdx.x;
    int wv = t >> 6, lane = t & 63, l4 = lane & 15, g = lane >> 4;
    int b = blockIdx.z;
    int i0 = blockIdx.x * 64, j0 = blockIdx.y * 128;
    int irow = i0 + wv * 16;
    const bf16x8* xh8 = (const bf16x8*)xh;
    const bf16x8* xl8 = (const bf16x8*)xl;

    int abase = (b * N + irow + l4) * 8 + g;
    bf16x8 ah[2], al[2];
    ah[0] = xh8[abase];
    ah[1] = xh8[abase + 4];
    al[0] = xl8[abase];
    al[1] = xl8[abase + 4];

    f32x4 acc[8];
#pragma unroll
    for (int ct = 0; ct < 8; ct++) acc[ct] = f32x4{0.f, 0.f, 0.f, 0.f};
#pragma unroll
    for (int ct = 0; ct < 8; ct++) {
        int j = j0 + 16 * ct + l4;
        int bbase = (b * N + j) * 8 + g;
        bf16x8 bh0 = xh8[bbase], bh1 = xh8[bbase + 4];
        bf16x8 bl0 = xl8[bbase], bl1 = xl8[bbase + 4];
        f32x4 a = acc[ct];
        a = __builtin_amdgcn_mfma_f32_16x16x32_bf16(ah[0], bh0, a, 0, 0, 0);
        a = __builtin_amdgcn_mfma_f32_16x16x32_bf16(ah[1], bh1, a, 0, 0, 0);
        a = __builtin_amdgcn_mfma_f32_16x16x32_bf16(al[0], bh0, a, 0, 0, 0);
        a = __builtin_amdgcn_mfma_f32_16x16x32_bf16(al[1], bh1, a, 0, 0, 0);
        a = __builtin_amdgcn_mfma_f32_16x16x32_bf16(ah[0], bl0, a, 0, 0, 0);
        a = __builtin_amdgcn_mfma_f32_16x16x32_bf16(ah[1], bl1, a, 0, 0, 0);
        acc[ct] = a;
    }
    float sqi[4];
#pragma unroll
    for (int r = 0; r < 4; r++) sqi[r] = sq[b * N + irow + 4 * g + r];
    float part = 0.f;
#pragma unroll
    for (int ct = 0; ct < 8; ct++) {
        int j = j0 + 16 * ct + l4;
        float sqj = sq[b * N + j];
#pragma unroll
        for (int r = 0; r < 4; r++) {
            float d2 = sqi[r] + sqj - 2.f * acc[ct][r];
            d2 = fmaxf(d2, 0.f);
            w[((size_t)b * N + irow + 4 * g + r) * N + j] = d2;
            part += (d2 > 1e-12f) ? sqrtf(d2) : 0.f;
        }
    }
#pragma unroll
    for (int m = 32; m; m >>= 1) part += __shfl_xor(part, m, 64);
    if (lane == 0) red[wv] = part;
    __syncthreads();
    if (t == 0) atomicAdd(d_sig, red[0] + red[1] + red[2] + red[3]);
}

// ---------------- wexp: w = exp(-d2/(2 sigma^2)), + sum w ----------------
__global__ __launch_bounds__(256) void k_wexp(float* __restrict__ w, const float* __restrict__ d_sig,
                                              float* __restrict__ d_wsum) {
    __shared__ float red[4];
    int idx = blockIdx.x * 256 + threadIdx.x;
    float sigma = d_sig[0] * (1.f / 4194304.f);
    float inv = 1.f / (2.f * sigma * sigma);
    float4 v = ((float4*)w)[idx];
    v.x = expf(-v.x * inv);
    v.y = expf(-v.y * inv);
    v.z = expf(-v.z * inv);
    v.w = expf(-v.w * inv);
    ((float4*)w)[idx] = v;
    float s = v.x + v.y + v.z + v.w;
#pragma unroll
    for (int m = 32; m; m >>= 1) s += __shfl_xor(s, m, 64);
    if ((threadIdx.x & 63) == 0) red[threadIdx.x >> 6] = s;
    __syncthreads();
    if (threadIdx.x == 0) atomicAdd(d_wsum, red[0] + red[1] + red[2] + red[3]);
}

// ---------------- attention: MFMA flash, 4 waves x 16 rows, 64-wide j tiles ----------------
__global__ __launch_bounds__(256) void k_attn(
    const short* __restrict__ qeh, const short* __restrict__ qel,
    const short* __restrict__ keh, const short* __restrict__ kel,
    const short* __restrict__ vT,
    const float* __restrict__ w, const float* __restrict__ spa,
    const float* __restrict__ d_wsum, float* __restrict__ aout) {
    __shared__ short Kh[64 * 64];
    __shared__ short Kl[64 * 64];
    __shared__ short Vt[64 * 64];
    __shared__ short P[4][16 * 64];
    int t = threadIdx.x;
    int wv = t >> 6, lane = t & 63, l4 = lane & 15, g = lane >> 4;
    int i0 = blockIdx.x * 64;
    int h = blockIdx.y, b = blockIdx.z, bh = b * H + h;
    float mu = d_wsum[0] * (1.f / 4194304.f);
    int irow = i0 + wv * 16;

    bf16x8 qh[2], ql[2];
    {
        const bf16x8* qh8 = (const bf16x8*)qeh;
        const bf16x8* ql8 = (const bf16x8*)qel;
        int base = (bh * N + irow + l4) * 8 + g;
#pragma unroll
        for (int mk = 0; mk < 2; mk++) {
            qh[mk] = qh8[base + 4 * mk];
            ql[mk] = ql8[base + 4 * mk];
        }
    }
    f32x4 O[4];
#pragma unroll
    for (int dt = 0; dt < 4; dt++) O[dt] = f32x4{0.f, 0.f, 0.f, 0.f};
    float m_r[4] = {-INFINITY, -INFINITY, -INFINITY, -INFINITY};
    float l_r[4] = {0.f, 0.f, 0.f, 0.f};

    const bf16x8* Kh8 = (const bf16x8*)Kh;
    const bf16x8* Kl8 = (const bf16x8*)Kl;
    const bf16x8* Vt8 = (const bf16x8*)Vt;

    for (int tile = 0; tile < 16; ++tile) {
        int j0 = tile * 64;
        __syncthreads();
        {
            const bf16x8* kh8 = (const bf16x8*)keh;
            const bf16x8* kl8 = (const bf16x8*)kel;
            const bf16x8* v8 = (const bf16x8*)vT;
            bf16x8* KhW = (bf16x8*)Kh;
            bf16x8* KlW = (bf16x8*)Kl;
            bf16x8* VtW = (bf16x8*)Vt;
#pragma unroll
            for (int rep = 0; rep < 2; rep++) {
                int c = t + 256 * rep;
                int j = c >> 3, s = c & 7;
                KhW[j * 8 + (s ^ (j & 7))] = kh8[(bh * N + j0 + j) * 8 + s];
                KlW[j * 8 + (s ^ (j & 7))] = kl8[(bh * N + j0 + j) * 8 + s];
                VtW[j * 8 + (s ^ (j & 7))] = v8[(bh * 64 + j) * (N / 8) + (j0 >> 3) + s];
            }
        }
        __syncthreads();
        f32x4 sc[4];
#pragma unroll
        for (int ct = 0; ct < 4; ct++) {
            int j = 16 * ct + l4;
            int sw = j & 7;
            bf16x8 kh0 = Kh8[j * 8 + ((g) ^ sw)];
            bf16x8 kh1 = Kh8[j * 8 + ((4 + g) ^ sw)];
            bf16x8 kl0 = Kl8[j * 8 + ((g) ^ sw)];
            bf16x8 kl1 = Kl8[j * 8 + ((4 + g) ^ sw)];
            f32x4 a = f32x4{0.f, 0.f, 0.f, 0.f};
            a = __builtin_amdgcn_mfma_f32_16x16x32_bf16(qh[0], kh0, a, 0, 0, 0);
            a = __builtin_amdgcn_mfma_f32_16x16x32_bf16(qh[1], kh1, a, 0, 0, 0);
            a = __builtin_amdgcn_mfma_f32_16x16x32_bf16(ql[0], kh0, a, 0, 0, 0);
            a = __builtin_amdgcn_mfma_f32_16x16x32_bf16(ql[1], kh1, a, 0, 0, 0);
            a = __builtin_amdgcn_mfma_f32_16x16x32_bf16(qh[0], kl0, a, 0, 0, 0);
            a = __builtin_amdgcn_mfma_f32_16x16x32_bf16(qh[1], kl1, a, 0, 0, 0);
            sc[ct] = a;
        }
        float p[4][4];
        float fr[4];
#pragma unroll
        for (int r = 0; r < 4; r++) {
            int i = irow + 4 * g + r;
            float mx = -INFINITY;
#pragma unroll
            for (int ct = 0; ct < 4; ct++) {
                int jg = j0 + 16 * ct + l4;
                float wv_ = w[((size_t)b * N + i) * N + jg];
                float sp = spa[i * N + jg];
                float spe = (wv_ < mu) ? 0.f : wv_;
                float val = sc[ct][r] * 0.125f * spe * sp;
                p[ct][r] = val;
                mx = fmaxf(mx, val);
            }
#pragma unroll
            for (int msk = 1; msk < 16; msk <<= 1) mx = fmaxf(mx, __shfl_xor(mx, msk, 64));
            float mo = m_r[r];
            float mn = fmaxf(mo, mx);
            float f = __expf(mo - mn);
            float s = 0.f;
#pragma unroll
            for (int ct = 0; ct < 4; ct++) {
                float e = __expf(p[ct][r] - mn);
                p[ct][r] = e;
                s += e;
            }
#pragma unroll
            for (int msk = 1; msk < 16; msk <<= 1) s += __shfl_xor(s, msk, 64);
            l_r[r] = l_r[r] * f + s;
            m_r[r] = mn;
            fr[r] = f;
        }
#pragma unroll
        for (int dt = 0; dt < 4; dt++) {
            O[dt][0] *= fr[0];
            O[dt][1] *= fr[1];
            O[dt][2] *= fr[2];
            O[dt][3] *= fr[3];
        }
        short* Pw = P[wv];
#pragma unroll
        for (int ct = 0; ct < 4; ct++) {
#pragma unroll
            for (int r = 0; r < 4; r++) {
                int row = 4 * g + r;
                int slot = ((l4 >> 3) + 2 * ct) ^ (row & 7);
                Pw[row * 64 + slot * 8 + (l4 & 7)] = f2bf(p[ct][r]);
            }
        }
        const bf16x8* Pr = (const bf16x8*)P[wv];
#pragma unroll
        for (int ks = 0; ks < 2; ks++) {
            bf16x8 pa = Pr[l4 * 8 + ((g + 4 * ks) ^ (l4 & 7))];
#pragma unroll
            for (int dt = 0; dt < 4; dt++) {
                int d = l4 + 16 * dt;
                bf16x8 bv = Vt8[d * 8 + ((g + 4 * ks) ^ (d & 7))];
                O[dt] = __builtin_amdgcn_mfma_f32_16x16x32_bf16(pa, bv, O[dt], 0, 0, 0);
            }
        }
    }
#pragma unroll
    for (int dt = 0; dt < 4; dt++) {
#pragma unroll
        for (int r = 0; r < 4; r++) {
            int i = irow + 4 * g + r;
            aout[((size_t)b * N + i) * INNER + h * 64 + l4 + 16 * dt] = O[dt][r] / l_r[r];
        }
    }
}

// ---------------- LN + GELU + out proj (8 rows/block) ----------------
__global__ __launch_bounds__(256) void k_out(const float* __restrict__ aout, const float* __restrict__ g,
                                             const float* __restrict__ be, const float* __restrict__ Wout,
                                             const float* __restrict__ bout, float* __restrict__ out) {
    __shared__ float y_s[8 * 512];
    int t = threadIdx.x;
    int wv = t >> 6, lane = t & 63;
    int r0 = blockIdx.x * 8;
#pragma unroll
    for (int rr = 0; rr < 2; rr++) {
        int rloc = wv * 2 + rr;
        const float* rp = aout + (size_t)(r0 + rloc) * 512;
        float4 v0 = ((const float4*)rp)[lane];
        float4 v1 = ((const float4*)rp)[lane + 64];
        float s1 = v0.x + v0.y + v0.z + v0.w + v1.x + v1.y + v1.z + v1.w;
        float s2 = v0.x * v0.x + v0.y * v0.y + v0.z * v0.z + v0.w * v0.w +
                   v1.x * v1.x + v1.y * v1.y + v1.z * v1.z + v1.w * v1.w;
#pragma unroll
        for (int m = 32; m; m >>= 1) {
            s1 += __shfl_xor(s1, m, 64);
            s2 += __shfl_xor(s2, m, 64);
        }
        float mean = s1 * (1.f / 512.f);
        float var = s2 * (1.f / 512.f) - mean * mean;
        float rstd = rsqrtf(var + 1e-5f);
        int c0 = 4 * lane, c1 = 4 * lane + 256;
        float4 o0, o1;
#pragma unroll
        for (int e = 0; e < 4; e++) {
            float yn = g[c0 + e] * (((float*)&v0)[e] - mean) * rstd + be[c0 + e];
            ((float*)&o0)[e] = 0.5f * yn * (1.f + erff(yn * 0.70710678118f));
            float ym = g[c1 + e] * (((float*)&v1)[e] - mean) * rstd + be[c1 + e];
            ((float*)&o1)[e] = 0.5f * ym * (1.f + erff(ym * 0.70710678118f));
        }
        ((float4*)(y_s + rloc * 512))[lane] = o0;
        ((float4*)(y_s + rloc * 512))[lane + 64] = o1;
    }
    __syncthreads();
    int o = t & 63, rg = t >> 6;
    float a0 = 0.f, a1 = 0.f;
#pragma unroll 4
    for (int c = 0; c < 512; c++) {
        float wv_ = Wout[c * 64 + o];
        a0 = fmaf(y_s[(rg * 2) * 512 + c], wv_, a0);
        a1 = fmaf(y_s[(rg * 2 + 1) * 512 + c], wv_, a1);
    }
    float bo = bout[o];
    out[(size_t)(r0 + rg * 2) * 64 + o] = a0 + bo;
    out[(size_t)(r0 + rg * 2 + 1) * 64 + o] = a1 + bo;
}

extern "C" void kernel_launch(void* const* d_in, const int* in_sizes, int n_in,
                              void* d_out, int out_size, void* d_ws, size_t ws_size,
                              hipStream_t stream) {
    const float* x = (const float*)d_in[0];
    const float* Wqkv = (const float*)d_in[1];
    const float* bqkv = (const float*)d_in[2];
    const float* lng = (const float*)d_in[3];
    const float* lnb = (const float*)d_in[4];
    const float* Wout = (const float*)d_in[5];
    const float* bout = (const float*)d_in[6];
    float* out = (float*)d_out;

    float* ws = (float*)d_ws;
    size_t off = 0;
    float* sq = ws + off;   off += (size_t)B * N;           // 4096
    float* scal = ws + off; off += 16;
    float* spa = ws + off;  off += (size_t)N * N;           // 1M
    float* wbuf = ws + off; off += (size_t)B * N * N;       // 4M
    float* aout = ws + off; off += (size_t)B * N * INNER;   // 2M
    short* sbase = (short*)(ws + off);
    size_t soff = 0;
    short* qeh = sbase + soff; soff += (size_t)B * H * N * DH;
    short* qel = sbase + soff; soff += (size_t)B * H * N * DH;
    short* keh = sbase + soff; soff += (size_t)B * H * N * DH;
    short* kel = sbase + soff; soff += (size_t)B * H * N * DH;
    short* vT  = sbase + soff; soff += (size_t)B * H * N * DH;
    short* xh  = sbase + soff; soff += (size_t)B * N * D;
    short* xl  = sbase + soff; soff += (size_t)B * N * D;
    short* Wh  = sbase + soff; soff += (size_t)D * C3;
    short* Wl  = sbase + soff; soff += (size_t)D * C3;

    // spa sigma/mu on host (input-independent)
    double ssum = 0.0;
    const double cnt = (double)N * (double)N;
    for (int dx = -15; dx <= 15; dx++)
        for (int dy = -15; dy <= 15; dy++)
            for (int dz = -3; dz <= 3; dz++) {
                double c = (double)(16 - abs(dx)) * (double)(16 - abs(dy)) * (double)(4 - abs(dz));
                double d2 = (double)(dx * dx + dy * dy + dz * dz);
                ssum += c * sqrt(d2);
            }
    double sigma = ssum / cnt;
    double inv2s2 = 1.0 / (2.0 * sigma * sigma);
    double wsum = 0.0;
    for (int dx = -15; dx <= 15; dx++)
        for (int dy = -15; dy <= 15; dy++)
            for (int dz = -3; dz <= 3; dz++) {
                double c = (double)(16 - abs(dx)) * (double)(16 - abs(dy)) * (double)(4 - abs(dz));
                double d2 = (double)(dx * dx + dy * dy + dz * dz);
                wsum += c * exp(-d2 * inv2s2);
            }
    double mu = wsum / cnt;

    hipMemsetAsync(scal, 0, 16 * sizeof(float), stream);
    k_conv<<<1024 + 24, 256, 0, stream>>>(x, Wqkv, xh, xl, sq, Wh, Wl);
    k_spa<<<(N * N) / 1024, 256, 0, stream>>>(spa, (float)inv2s2, (float)mu);
    k_qkvm<<<dim3(64, 12), 256, 0, stream>>>(xh, xl, Wh, Wl, bqkv, qeh, qel, keh, kel, vT);
    k_gramm<<<dim3(16, 8, B), 256, 0, stream>>>(xh, xl, sq, wbuf, scal);
    k_wexp<<<4096, 256, 0, stream>>>(wbuf, scal, scal + 1);
    k_attn<<<dim3(N / 64, H, B), 256, 0, stream>>>(qeh, qel, keh, kel, vT, wbuf, spa, scal + 1, aout);
    k_out<<<512, 256, 0, stream>>>(aout, lng, lnb, Wout, bout, out);
}